// Round 6
// baseline (380.395 us; speedup 1.0000x reference)
//
#include <hip/hip_runtime.h>
#include <stdint.h>

#define LOG2E  1.44269504088896f
#define QSCALE (0.125f * LOG2E)   // folded into Q: sacc is already the exp2 argument

typedef float    f32x4_t  __attribute__((ext_vector_type(4)));
typedef float    f32x16_t __attribute__((ext_vector_type(16)));
typedef _Float16 f16x8_t  __attribute__((ext_vector_type(8)));
typedef _Float16 f16x2_t  __attribute__((ext_vector_type(2)));

#if __has_builtin(__builtin_amdgcn_exp2f)
#define EXP2F(x) __builtin_amdgcn_exp2f(x)
#else
#define EXP2F(x) exp2f(x)
#endif

__device__ __forceinline__ float rowsum2(f16x2_t p, float acc) {
#if __has_builtin(__builtin_amdgcn_fdot2)
  return __builtin_amdgcn_fdot2(p, (f16x2_t){(_Float16)1.0f, (_Float16)1.0f}, acc, false);
#else
  return acc + (float)p[0] + (float)p[1];
#endif
}

// ---------------- mask all-zero scan ----------------
__global__ void mask_scan_kernel(const float* __restrict__ m, int* __restrict__ flag) {
  const float* p = m + (size_t)blockIdx.x * 8192 + (size_t)threadIdx.x * 4;
  unsigned acc = 0;
#pragma unroll
  for (int i = 0; i < 8; ++i) {
    f32x4_t v = *(const f32x4_t*)(p + (size_t)i * 1024);
    acc |= __float_as_uint(v[0]) | __float_as_uint(v[1]) |
           __float_as_uint(v[2]) | __float_as_uint(v[3]);
  }
  acc &= 0x7fffffffu;
  if (acc) atomicOr(flag, 1);
}

// ---------------- pre-convert Q (scaled) and K to fp16 ----------------
__global__ void convert_qk_kernel(const float* __restrict__ Q, const float* __restrict__ K,
                                  _Float16* __restrict__ Qh, _Float16* __restrict__ Kh) {
  const size_t idx = ((size_t)blockIdx.x * 256 + threadIdx.x) * 8;
  {
    f32x4_t a = *(const f32x4_t*)(Q + idx);
    f32x4_t b = *(const f32x4_t*)(Q + idx + 4);
    union { _Float16 h[8]; uint4 q; } U;
#pragma unroll
    for (int j = 0; j < 4; ++j) { U.h[j] = (_Float16)(a[j] * QSCALE); U.h[4 + j] = (_Float16)(b[j] * QSCALE); }
    *(uint4*)(Qh + idx) = U.q;
  }
  {
    f32x4_t a = *(const f32x4_t*)(K + idx);
    f32x4_t b = *(const f32x4_t*)(K + idx + 4);
    union { _Float16 h[8]; uint4 q; } U;
#pragma unroll
    for (int j = 0; j < 4; ++j) { U.h[j] = (_Float16)a[j]; U.h[4 + j] = (_Float16)b[j]; }
    *(uint4*)(Kh + idx) = U.q;
  }
}

// ---------------- pre-transpose V to fp16 [head][feat][seq] ----------------
__global__ void transpose_v_kernel(const float* __restrict__ V, _Float16* __restrict__ Vth) {
  __shared__ __align__(16) _Float16 T[64 * 72];
  const int tid  = threadIdx.x;
  const int head = blockIdx.x >> 6;
  const int st   = blockIdx.x & 63;
  const size_t hoff = (size_t)head * 4096 * 64;

  const int sl    = tid >> 2;
  const int fbase = (tid & 3) * 16;
  const float* src = V + hoff + (size_t)(st * 64 + sl) * 64 + fbase;
#pragma unroll
  for (int c = 0; c < 4; ++c) {
    f32x4_t a = *(const f32x4_t*)(src + c * 4);
#pragma unroll
    for (int j = 0; j < 4; ++j) T[(fbase + c * 4 + j) * 72 + sl] = (_Float16)a[j];
  }
  __syncthreads();
  const int feat = tid >> 2;
  const int sb   = (tid & 3) * 16;
  uint4 r0 = *(const uint4*)&T[feat * 72 + sb];
  uint4 r1 = *(const uint4*)&T[feat * 72 + sb + 8];
  _Float16* dst = Vth + hoff + (size_t)feat * 4096 + st * 64 + sb;
  *(uint4*)(dst)     = r0;
  *(uint4*)(dst + 8) = r1;
}

// ---------------- SDPA core v4: NO LDS, direct global MFMA fragments ----------------
// r3 register shape (32 q/wave, VGPR ~60-110, no spill) + zero barriers.
// All fragments are 16B-contiguous in the preprocessed layouts:
//   K A-frag (sigma-row): Kh[(kbase+kb*32+sig)*64 + kh*16 + 8*h2]
//   V B-frag:             Vth[feat*4096 + kbase + f*16 + 8*h2]
// Working set/CU = 2 heads x 1 MB -> L1/L2-resident (2 heads per XCD swizzle).
// sigma trick: PV A-fragments are lane-local sacc regs (no P round-trip).
__launch_bounds__(256, 2)
__global__ void sdpa_kernel4(const _Float16* __restrict__ Qh, const _Float16* __restrict__ Kh,
                             const _Float16* __restrict__ Vth, const float* __restrict__ Mg,
                             float* __restrict__ Og, const int* __restrict__ flag) {
  const int t    = threadIdx.x;
  const int bid  = blockIdx.x;                           // 0..511
  const int hh   = ((bid & 7) << 1) | ((bid >> 3) & 1);  // 2 heads per XCD
  const int qt   = bid >> 4;                             // 0..31
  const int w    = t >> 6;
  const int lane = t & 63;
  const int n    = lane & 31;
  const int h2   = lane >> 5;
  const int sig  = (n & 0x13) | ((n >> 1) & 4) | ((n << 1) & 8);  // swap bits 2,3
  const bool has_mask = (*flag) != 0;

  const size_t hoff = (size_t)hh * 4096 * 64;
  const int qcol = qt * 128 + w * 32 + n;

  // ---- Q B-fragment: lane holds Q[qcol][kh*16 + 8*h2 + j] (pre-scaled) ----
  f16x8_t qf[4];
  {
    const _Float16* qp = Qh + hoff + (size_t)qcol * 64 + 8 * h2;
#pragma unroll
    for (int kh = 0; kh < 4; ++kh) qf[kh] = *(const f16x8_t*)(qp + kh * 16);
  }

  // fragment base pointers (loop-invariant parts hoisted)
  const _Float16* kfp = Kh  + hoff + (size_t)sig * 64 + 8 * h2;          // + (kbase+kb*32)*64 + kh*16
  const _Float16* vf0 = Vth + hoff + (size_t)n * 4096 + 8 * h2;          // + kbase + f*16
  const _Float16* vf1 = Vth + hoff + (size_t)(32 + n) * 4096 + 8 * h2;

  f32x16_t o0 = {0.f,0.f,0.f,0.f,0.f,0.f,0.f,0.f,0.f,0.f,0.f,0.f,0.f,0.f,0.f,0.f};
  f32x16_t o1 = o0;
  float lacc = 0.0f;

#pragma unroll 1
  for (int kt = 0; kt < 64; ++kt) {
    const int kbase = kt * 64;

#pragma unroll
    for (int kb = 0; kb < 2; ++kb) {
      // ---- K A-fragments direct from global (L1/L2-hit) ----
      const _Float16* kp = kfp + (size_t)(kbase + kb * 32) * 64;
      f16x8_t ka[4];
#pragma unroll
      for (int kh = 0; kh < 4; ++kh) ka[kh] = *(const f16x8_t*)(kp + kh * 16);

      f32x16_t s = {0.f,0.f,0.f,0.f,0.f,0.f,0.f,0.f,0.f,0.f,0.f,0.f,0.f,0.f,0.f,0.f};
#pragma unroll
      for (int kh = 0; kh < 4; ++kh)
        s = __builtin_amdgcn_mfma_f32_32x32x16_f16(ka[kh], qf[kh], s, 0, 0, 0);

      // ---- softmax + PV: frag f = 2*kb + a uses regs 8a..8a+7, lane-local ----
#pragma unroll
      for (int a = 0; a < 2; ++a) {
        const int f = kb * 2 + a;
        const f16x8_t v0 = *(const f16x8_t*)(vf0 + kbase + f * 16);
        const f16x8_t v1 = *(const f16x8_t*)(vf1 + kbase + f * 16);

        union { _Float16 h[8]; f16x8_t v; f16x2_t p2[4]; } F;
        f32x4_t m0, m1;
        if (has_mask) {
          const float* mp = Mg + (size_t)qcol * 4096 + kbase + kb * 32 + 16 * a + 8 * h2;
          m0 = *(const f32x4_t*)(mp);
          m1 = *(const f32x4_t*)(mp + 4);
        }
#pragma unroll
        for (int idx = 0; idx < 8; ++idx) {
          float x = s[8 * a + idx];
          if (has_mask) {
            float m = (idx < 4) ? m0[idx] : m1[idx - 4];
            x = __builtin_fmaf(m, LOG2E, x);
          }
          F.h[idx] = (_Float16)EXP2F(x);
        }
#pragma unroll
        for (int u = 0; u < 4; ++u) lacc = rowsum2(F.p2[u], lacc);
        o0 = __builtin_amdgcn_mfma_f32_32x32x16_f16(F.v, v0, o0, 0, 0, 0);
        o1 = __builtin_amdgcn_mfma_f32_32x32x16_f16(F.v, v1, o1, 0, 0, 0);
      }
    }
  }

  // ---- epilogue: l per q-column, normalize, store ----
  float lq = lacc + __shfl_xor(lacc, 32);
  float* op = Og + hoff;
#pragma unroll
  for (int r2 = 0; r2 < 4; ++r2) {
#pragma unroll
    for (int rr = 0; rr < 4; ++rr) {
      const int reg  = r2 * 4 + rr;
      const int qrow = rr + 8 * r2 + 4 * h2;      // C/D row mapping (m74/m101)
      float lr  = __shfl(lq, qrow);
      float inv = 1.0f / lr;
      const size_t row = (size_t)(qt * 128 + w * 32 + qrow) * 64;
      op[row + n]      = o0[reg] * inv;
      op[row + 32 + n] = o1[reg] * inv;
    }
  }
}

// ---------------- fallback (ws too small): r3 structure, in-kernel converts ----
__launch_bounds__(256, 2)
__global__ void sdpa_kernel_fb(const float* __restrict__ Qg, const float* __restrict__ Kg,
                               const float* __restrict__ Vg, const float* __restrict__ Mg,
                               float* __restrict__ Og, const int* __restrict__ flag) {
  __shared__ __align__(16) _Float16 Ks[64 * 72];
  __shared__ __align__(16) _Float16 Vt[64 * 72];

  const int tid  = threadIdx.x;
  const int bid  = blockIdx.x;
  const int hh   = ((bid & 7) << 1) | ((bid >> 3) & 1);
  const int qt   = bid >> 4;
  const int w    = tid >> 6;
  const int lane = tid & 63;
  const int n    = lane & 31;
  const int h2   = lane >> 5;
  const int sig  = (n & 0x13) | ((n >> 1) & 4) | ((n << 1) & 8);
  const bool has_mask = (*flag) != 0;

  const size_t hoff = (size_t)hh * 4096 * 64;
  const int qcol = qt * 128 + w * 32 + n;

  f16x8_t qf[4];
  {
    const float* qp = Qg + hoff + (size_t)qcol * 64 + 8 * h2;
#pragma unroll
    for (int kh = 0; kh < 4; ++kh) {
      f32x4_t a = *(const f32x4_t*)(qp + kh * 16);
      f32x4_t b = *(const f32x4_t*)(qp + kh * 16 + 4);
      union { _Float16 h[8]; f16x8_t v; } U;
#pragma unroll
      for (int j = 0; j < 4; ++j) { U.h[j] = (_Float16)(a[j] * QSCALE); U.h[4 + j] = (_Float16)(b[j] * QSCALE); }
      qf[kh] = U.v;
    }
  }

  f32x16_t o0 = {0.f,0.f,0.f,0.f,0.f,0.f,0.f,0.f,0.f,0.f,0.f,0.f,0.f,0.f,0.f,0.f};
  f32x16_t o1 = o0;
  float lacc = 0.0f;

#pragma unroll 1
  for (int kt = 0; kt < 64; ++kt) {
    const int kbase = kt * 64;
    const float* kp = Kg + hoff + (size_t)(kbase + (tid >> 2)) * 64 + (tid & 3) * 16;
    f32x4_t k0 = *(const f32x4_t*)(kp + 0);
    f32x4_t k1 = *(const f32x4_t*)(kp + 4);
    f32x4_t k2 = *(const f32x4_t*)(kp + 8);
    f32x4_t k3 = *(const f32x4_t*)(kp + 12);
    const float* vp = Vg + hoff + (size_t)(kbase + (tid >> 5) * 8) * 64 + (tid & 31);
    float vlo[8], vhi[8];
#pragma unroll
    for (int j = 0; j < 8; ++j) { vlo[j] = vp[(size_t)j * 64]; vhi[j] = vp[(size_t)j * 64 + 32]; }

    f32x4_t mk[2][2][2];
    if (has_mask) {
      const float* mp = Mg + (size_t)qcol * 4096 + kbase + 8 * h2;
#pragma unroll
      for (int kb = 0; kb < 2; ++kb)
#pragma unroll
        for (int a = 0; a < 2; ++a)
#pragma unroll
          for (int b = 0; b < 2; ++b)
            mk[kb][a][b] = *(const f32x4_t*)(mp + kb * 32 + 16 * a + 4 * b);
    }

    __syncthreads();
    {
      union { _Float16 h[8]; uint4 q; } A, B;
#pragma unroll
      for (int j = 0; j < 4; ++j) {
        A.h[j] = (_Float16)k0[j];  A.h[4 + j] = (_Float16)k1[j];
        B.h[j] = (_Float16)k2[j];  B.h[4 + j] = (_Float16)k3[j];
      }
      *(uint4*)&Ks[(tid >> 2) * 72 + (tid & 3) * 16]     = A.q;
      *(uint4*)&Ks[(tid >> 2) * 72 + (tid & 3) * 16 + 8] = B.q;
      union { _Float16 h[8]; uint4 q; } C, D;
#pragma unroll
      for (int j = 0; j < 8; ++j) { C.h[j] = (_Float16)vlo[j]; D.h[j] = (_Float16)vhi[j]; }
      *(uint4*)&Vt[(tid & 31) * 72 + (tid >> 5) * 8]        = C.q;
      *(uint4*)&Vt[((tid & 31) + 32) * 72 + (tid >> 5) * 8] = D.q;
    }
    __syncthreads();

#pragma unroll
    for (int kb = 0; kb < 2; ++kb) {
      f32x16_t acc = {0.f,0.f,0.f,0.f,0.f,0.f,0.f,0.f,0.f,0.f,0.f,0.f,0.f,0.f,0.f,0.f};
#pragma unroll
      for (int kh = 0; kh < 4; ++kh) {
        const f16x8_t ka = *(const f16x8_t*)&Ks[(kb * 32 + sig) * 72 + kh * 16 + 8 * h2];
        acc = __builtin_amdgcn_mfma_f32_32x32x16_f16(ka, qf[kh], acc, 0, 0, 0);
      }
#pragma unroll
      for (int a = 0; a < 2; ++a) {
        union { _Float16 h[8]; f16x8_t v; f16x2_t p2[4]; } F;
#pragma unroll
        for (int idx = 0; idx < 8; ++idx) {
          float x = acc[8 * a + idx];
          if (has_mask) x = __builtin_fmaf(mk[kb][a][idx >> 2][idx & 3], LOG2E, x);
          F.h[idx] = (_Float16)EXP2F(x);
        }
#pragma unroll
        for (int u = 0; u < 4; ++u) lacc = rowsum2(F.p2[u], lacc);
        const int f = kb * 2 + a;
        const f16x8_t v0 = *(const f16x8_t*)&Vt[n * 72 + f * 16 + 8 * h2];
        o0 = __builtin_amdgcn_mfma_f32_32x32x16_f16(F.v, v0, o0, 0, 0, 0);
        const f16x8_t v1 = *(const f16x8_t*)&Vt[(32 + n) * 72 + f * 16 + 8 * h2];
        o1 = __builtin_amdgcn_mfma_f32_32x32x16_f16(F.v, v1, o1, 0, 0, 0);
      }
    }
  }

  float lq = lacc + __shfl_xor(lacc, 32);
  float* op = Og + hoff;
#pragma unroll
  for (int r2 = 0; r2 < 4; ++r2) {
#pragma unroll
    for (int rr = 0; rr < 4; ++rr) {
      const int reg  = r2 * 4 + rr;
      const int qrow = rr + 8 * r2 + 4 * h2;
      float lr  = __shfl(lq, qrow);
      float inv = 1.0f / lr;
      const size_t row = (size_t)(qt * 128 + w * 32 + qrow) * 64;
      op[row + n]      = o0[reg] * inv;
      op[row + 32 + n] = o1[reg] * inv;
    }
  }
}

extern "C" void kernel_launch(void* const* d_in, const int* in_sizes, int n_in,
                              void* d_out, int out_size, void* d_ws, size_t ws_size,
                              hipStream_t stream) {
  const float* Q = (const float*)d_in[0];
  const float* K = (const float*)d_in[1];
  const float* V = (const float*)d_in[2];
  const float* M = (const float*)d_in[3];
  float* O = (float*)d_out;

  const size_t NELEM = (size_t)16 * 4096 * 64;
  const size_t need  = 256 + 3 * NELEM * sizeof(_Float16);
  int* flag = (int*)d_ws;

  hipMemsetAsync(flag, 0, sizeof(int), stream);
  mask_scan_kernel<<<2048, 256, 0, stream>>>(M, flag);

  if (ws_size >= need) {
    _Float16* Qh  = (_Float16*)((char*)d_ws + 256);
    _Float16* Kh  = Qh + NELEM;
    _Float16* Vth = Kh + NELEM;
    convert_qk_kernel<<<2048, 256, 0, stream>>>(Q, K, Qh, Kh);
    transpose_v_kernel<<<1024, 256, 0, stream>>>(V, Vth);
    sdpa_kernel4<<<512, 256, 0, stream>>>(Qh, Kh, Vth, M, O, flag);
  } else {
    sdpa_kernel_fb<<<512, 256, 0, stream>>>(Q, K, V, M, O, flag);
  }
}